// Round 22
// baseline (76.855 us; speedup 1.0000x reference)
//
#include <hip/hip_runtime.h>
#include <math.h>

#define N_NODES 4096
#define H 64
#define NE 24576
#define KNN 15
#define KBUF 832
#define BSLOT 32   // bucket slots per row/col (max observed degree ~22, Poisson(6))

typedef float vfloat4 __attribute__((ext_vector_type(4)));

__device__ __forceinline__ int mbcnt64(unsigned long long m) {
    int lo = __builtin_amdgcn_mbcnt_lo((unsigned int)m, 0u);
    return __builtin_amdgcn_mbcnt_hi((unsigned int)(m >> 32), lo);
}

// ---------------- init: zero cursors + xp = (x,y,z,|x|^2) + transpose Wp/Wq/Wk ----------------
__global__ __launch_bounds__(256) void k_init(int* __restrict__ cursR, int* __restrict__ cursC,
                                              const float* __restrict__ x, float4* __restrict__ xp,
                                              const float* __restrict__ Wp, const float* __restrict__ Wq,
                                              const float* __restrict__ Wk,
                                              float* __restrict__ WpT, float* __restrict__ WqT,
                                              float* __restrict__ WkT) {
    int tid = blockIdx.x * 256 + threadIdx.x;
    if (tid < N_NODES) {
        cursR[tid] = 0; cursC[tid] = 0;
        float a = x[tid * 3], b = x[tid * 3 + 1], c = x[tid * 3 + 2];
        xp[tid] = make_float4(a, b, c, a * a + b * b + c * c);
    }
    if (tid < H * H) {
        int k = tid >> 6, h = tid & 63;      // WT[k][h] = W[h][k]
        WpT[k * H + h] = Wp[h * H + k];
        WqT[k * H + h] = Wq[h * H + k];
        WkT[k * H + h] = Wk[h * H + k];
    }
}

// ---------------- kNN: 1 wave = 1 block; 8 cand/lane/iter; filtered iter-0 (no bulk store) ----------------
__global__ __launch_bounds__(64) void k_knn(const float4* __restrict__ xp, int* __restrict__ knn_idx,
                                            const int* __restrict__ edges, int* __restrict__ cursR,
                                            int* __restrict__ cursC, int* __restrict__ colRb,
                                            int* __restrict__ c2cb, float2* __restrict__ jav) {
    __shared__ unsigned long long cb[KBUF];         // 6656 B
    __shared__ unsigned long long plane[12][64];    // 6144 B  per-lane strips
    const int lane = threadIdx.x;
    const int i = blockIdx.x;

    // scatter piggyback: blocks 0..383 cover all 24576 edges (cursors zeroed by k_init)
    if (i < NE / 64) {
        int e = i * 64 + lane;
        int r = edges[e], c = edges[NE + e];
        int p = atomicAdd(&cursR[r], 1);
        int q = atomicAdd(&cursC[c], 1);
        if (p < BSLOT && q < BSLOT) {
            colRb[r * BSLOT + p] = c;
            c2cb[r * BSLOT + p] = c * BSLOT + q;
            ((int*)jav)[2 * (c * BSLOT + q)] = r;
        }
    }

    const float4 pi = xp[i];
    unsigned long long tauKey;
    int cnt = 0;
    int mycnt = 0;

    auto sort64 = [&](unsigned long long key) -> unsigned long long {
#pragma unroll
        for (int k = 2; k <= 64; k <<= 1) {
#pragma unroll
            for (int j = 32; j > 0; j >>= 1) {
                if (j >= k) continue;
                unsigned long long other = __shfl_xor(key, j);
                bool asc = ((lane & k) == 0);
                bool takeMin = (((lane & j) == 0) == asc);
                bool less = key < other;
                key = (takeMin == less) ? key : other;
            }
        }
        return key;
    };

    // keep survivors <= T (T = 15th of lane-mins >= exact 15th); preserves all true top-15
    auto tighten = [&]() {
        __builtin_amdgcn_wave_barrier();
        int n = (cnt + 63) >> 6;
        unsigned long long v[13];
        unsigned long long kmin = ~0ull;
#pragma unroll
        for (int t = 0; t < 13; ++t) {
            v[t] = ~0ull;
            if (t < n) {
                int s = t * 64 + lane;
                if (s < cnt) v[t] = cb[s];
                kmin = (v[t] < kmin) ? v[t] : kmin;
            }
        }
        unsigned long long T = __shfl(sort64(kmin), 14);
        __builtin_amdgcn_wave_barrier();
        int m = 0;
#pragma unroll
        for (int t = 0; t < 13; ++t) {
            if (t < n) {
                bool pred = (v[t] <= T);
                unsigned long long mk = __ballot(pred);
                if (pred) cb[m + mbcnt64(mk)] = v[t];
                m += __popcll(mk);
            }
        }
        cnt = m;
        tauKey = T;
        __builtin_amdgcn_wave_barrier();
    };

    // drain per-lane strips into cb (ballot-prefix per slot; expected <=1 round)
    auto merge = [&]() {
        __builtin_amdgcn_wave_barrier();
        int maxc = mycnt;
#pragma unroll
        for (int o = 32; o > 0; o >>= 1) { int u = __shfl_xor(maxc, o); maxc = (u > maxc) ? u : maxc; }
        for (int s = 0; s < maxc; ++s) {
            bool pred = (s < mycnt);
            unsigned long long mk = __ballot(pred);
            if (pred) cb[cnt + mbcnt64(mk)] = plane[s][lane];
            cnt += __popcll(mk);
        }
        mycnt = 0;
        __builtin_amdgcn_wave_barrier();
    };

    // iter 0: 512 candidates (8/lane); tau = 15th of sorted lane-mins; filtered append (<= keeps top-15)
    {
        unsigned long long keys[8];
        unsigned long long kmin = ~0ull;
#pragma unroll
        for (int t = 0; t < 8; ++t) {
            int j = t * 64 + lane;
            float4 pj = xp[j];
            float d = pi.w + pj.w - 2.0f * (pi.x * pj.x + pi.y * pj.y + pi.z * pj.z);
            unsigned long long key = ((unsigned long long)__float_as_uint(d) << 32) | (unsigned)j;
            if (j == i) key = ~0ull;
            keys[t] = key;
            kmin = (key < kmin) ? key : kmin;
        }
        tauKey = __shfl(sort64(kmin), 14);   // every lane has a finite min -> tau finite
#pragma unroll
        for (int t = 0; t < 8; ++t) {
            if (keys[t] <= tauKey) { plane[mycnt][lane] = keys[t]; ++mycnt; }
        }
        if (__any(mycnt > 4)) { merge(); tighten(); }
    }

    // iters 1..7: 8 candidates/lane, per-lane conditional appends only
    for (int iter = 1; iter < 8; ++iter) {
        const int jb = iter * 512;
        float4 p[8];
#pragma unroll
        for (int t = 0; t < 8; ++t) p[t] = xp[jb + t * 64 + lane];
#pragma unroll
        for (int t = 0; t < 8; ++t) {
            float d = pi.w + p[t].w - 2.0f * (pi.x * p[t].x + pi.y * p[t].y + pi.z * p[t].z);
            int j = jb + t * 64 + lane;
            unsigned long long key = ((unsigned long long)__float_as_uint(d) << 32) | (unsigned)j;
            if ((key < tauKey) && (j != i)) { plane[mycnt][lane] = key; ++mycnt; }
        }
        if (__any(mycnt > 4)) { merge(); tighten(); }   // start-of-iter mycnt<=4, +8 -> <=12 slots
    }

    merge();
    tighten();
    if (cnt > 64) tighten();
    unsigned long long fin = (lane < cnt) ? cb[lane] : ~0ull;
    fin = sort64(fin);
    if (lane < KNN) knn_idx[i * KNN + lane] = (int)(fin & 0xffffffffu);
}

// ---------------- DevConv max-agg + WpT/WqT/WkT (coalesced): 4 waves/block, wave per node ----------------
__global__ __launch_bounds__(256) void k_agg_feat_qk(const float4* __restrict__ xp,
                                                     const int* __restrict__ cursR, const int* __restrict__ colRb,
                                                     const int* __restrict__ knn_idx, const float* __restrict__ Wt,
                                                     const float* __restrict__ WpT, const float* __restrict__ WqT,
                                                     const float* __restrict__ WkT,
                                                     float* __restrict__ qb, float* __restrict__ kb) {
    __shared__ float mrow[4][64];
    __shared__ float frow[4][64];
    int w = threadIdx.x >> 6, lane = threadIdx.x & 63;
    int i = blockIdx.x * 4 + w;
    float w0 = Wt[lane * 3], w1 = Wt[lane * 3 + 1], w2 = Wt[lane * 3 + 2];
    float4 pi = xp[i];
    float m = -INFINITY;
    int deg = cursR[i];
    for (int s = 0; s < deg; ++s) {
        float4 pj = xp[colRb[i * BSLOT + s]];
        m = fmaxf(m, w0 * (pj.x - pi.x) + w1 * (pj.y - pi.y) + w2 * (pj.z - pi.z));
    }
    for (int t = 0; t < KNN; ++t) {
        float4 pj = xp[knn_idx[i * KNN + t]];
        m = fmaxf(m, w0 * (pj.x - pi.x) + w1 * (pj.y - pi.y) + w2 * (pj.z - pi.z));
    }
    if (!(m > -INFINITY)) m = 0.0f;
    mrow[w][lane] = m;
    __syncthreads();
    float f = 0.f;
    for (int k2 = 0; k2 < H; ++k2) f += WpT[k2 * H + lane] * mrow[w][k2];   // coalesced
    frow[w][lane] = f;
    __syncthreads();
    float qv = 0.f, kv = 0.f;
    for (int k2 = 0; k2 < H; ++k2) {
        float fr = frow[w][k2];
        qv += WqT[k2 * H + lane] * fr;                                      // coalesced
        kv += WkT[k2 * H + lane] * fr;                                      // coalesced
    }
    qb[i * H + lane] = qv;
    kb[i * H + lane] = kv;
}

// ---------------- fused attention + softmax: 4 waves per block, fully in-register ----------------
__global__ __launch_bounds__(256) void k_attsm(const int* __restrict__ cursR, const int* __restrict__ colRb,
                                               const int* __restrict__ c2cb,
                                               const float* __restrict__ qb, const float* __restrict__ kb,
                                               float* __restrict__ attnRb, float2* __restrict__ jav) {
    int w = threadIdx.x >> 6, lane = threadIdx.x & 63;
    int i = blockIdx.x * 4 + w;
    int deg = cursR[i];
    if (deg == 0) return;                     // wave-level exit; kernel has no barriers
    float qv = qb[i * H + lane];
    float m = -INFINITY, myv = 0.f;
    for (int s = 0; s < deg; ++s) {
        int c = colRb[i * BSLOT + s];         // wave-uniform broadcast
        float v = qv * kb[c * H + lane];      // coalesced
#pragma unroll
        for (int o = 32; o > 0; o >>= 1) v += __shfl_xor(v, o);
        if (lane == s) myv = v;               // lane s keeps score s
        m = fmaxf(m, v);                      // wave-uniform
    }
    float ex = (lane < deg) ? expf(myv - m) : 0.f;
    float den = ex;
#pragma unroll
    for (int o = 32; o > 0; o >>= 1) den += __shfl_xor(den, o);
    if (lane < deg) {
        float a = ex / den;
        attnRb[i * BSLOT + lane] = a;
        ((float*)jav)[2 * c2cb[i * BSLOT + lane] + 1] = a;   // av into jav.y
    }
}

// ---------------- final: block per row; parallel prep + (s,a)-parallel leaves; no pair list ----------------
__global__ __launch_bounds__(256) void k_final_row(const int* __restrict__ cursR, const int* __restrict__ cursC,
                                                   const int* __restrict__ colRb, const float* __restrict__ attnRb,
                                                   const float2* __restrict__ jav,
                                                   float* __restrict__ out) {
    __shared__ __align__(16) float Orow[N_NODES];
    __shared__ int   cS[BSLOT];
    __shared__ float svS[BSLOT];
    __shared__ int   dS[BSLOT];
    int r = blockIdx.x;
    int tid = threadIdx.x;
    vfloat4* O4 = (vfloat4*)Orow;
    vfloat4 z = {0.f, 0.f, 0.f, 0.f};
    int deg = cursR[r];

    if (tid >= 64) {
        // waves 1-3: zero the accumulator row
        for (int t = tid - 64; t < N_NODES / 4; t += 192) O4[t] = z;
    } else if (tid < deg) {
        // wave 0, lanes 0..deg-1 in parallel: neighbor c, its attn, its A-row degree
        int c = colRb[r * BSLOT + tid];
        cS[tid]  = c;
        svS[tid] = attnRb[r * BSLOT + tid];
        dS[tid]  = cursR[c];
    }
    __syncthreads();

    // leaf phase: thread per (s, a) slot; a strides the A-row of neighbor s
    int tot = deg * BSLOT;
    for (int idx = tid; idx < tot; idx += 256) {
        int s = idx >> 5, a = idx & (BSLOT - 1);
        if (a < dS[s]) {
            int c2 = colRb[cS[s] * BSLOT + a];
            float sv = svS[s];
            int b1 = cursC[c2];
            for (int b = 0; b < b1; ++b) {
                float2 v = jav[c2 * BSLOT + b];
                atomicAdd(&Orow[__float_as_int(v.x)], sv * v.y);
            }
        }
    }
    __syncthreads();

    vfloat4* o4 = (vfloat4*)(out + (size_t)r * N_NODES);
#pragma unroll
    for (int t = 0; t < N_NODES / 4 / 256; ++t)
        __builtin_nontemporal_store(O4[tid + t * 256], &o4[tid + t * 256]);
}

extern "C" void kernel_launch(void* const* d_in, const int* in_sizes, int n_in,
                              void* d_out, int out_size, void* d_ws, size_t ws_size,
                              hipStream_t stream) {
    const float* x    = (const float*)d_in[0];
    const int* edges  = (const int*)d_in[1];
    const float* Wt   = (const float*)d_in[2];
    const float* Wp   = (const float*)d_in[3];
    const float* Wq   = (const float*)d_in[4];
    const float* Wk   = (const float*)d_in[5];
    float* out = (float*)d_out;

    char* w = (char*)d_ws;
    size_t off = 0;
    auto alloc = [&](size_t bytes) -> void* {
        void* p = w + off;
        off += (bytes + 255) & ~(size_t)255;
        return p;
    };
    float4* xp      = (float4*)alloc((size_t)N_NODES * 16);
    int*   knn      = (int*)  alloc((size_t)N_NODES * KNN * 4);
    float* qb       = (float*)alloc((size_t)N_NODES * H * 4);
    float* kb       = (float*)alloc((size_t)N_NODES * H * 4);
    int*   cursR    = (int*)  alloc((size_t)N_NODES * 4);
    int*   cursC    = (int*)  alloc((size_t)N_NODES * 4);
    int*   colRb    = (int*)  alloc((size_t)N_NODES * BSLOT * 4);
    int*   c2cb     = (int*)  alloc((size_t)N_NODES * BSLOT * 4);
    float* attnRb   = (float*)alloc((size_t)N_NODES * BSLOT * 4);
    float2* jav     = (float2*)alloc((size_t)N_NODES * BSLOT * 8);
    float* WpT      = (float*)alloc((size_t)H * H * 4);
    float* WqT      = (float*)alloc((size_t)H * H * 4);
    float* WkT      = (float*)alloc((size_t)H * H * 4);

    k_init<<<(N_NODES + 255) / 256, 256, 0, stream>>>(cursR, cursC, x, xp, Wp, Wq, Wk, WpT, WqT, WkT);
    k_knn<<<N_NODES, 64, 0, stream>>>(xp, knn, edges, cursR, cursC, colRb, c2cb, jav);
    k_agg_feat_qk<<<N_NODES / 4, 256, 0, stream>>>(xp, cursR, colRb, knn, Wt, WpT, WqT, WkT, qb, kb);
    k_attsm<<<N_NODES / 4, 256, 0, stream>>>(cursR, colRb, c2cb, qb, kb, attnRb, jav);
    k_final_row<<<N_NODES, 256, 0, stream>>>(cursR, cursC, colRb, attnRb, jav, out);
}

// Round 23
// 70.750 us; speedup vs baseline: 1.0863x; 1.0863x over previous
//
#include <hip/hip_runtime.h>
#include <math.h>

#define N_NODES 4096
#define H 64
#define NE 24576
#define KNN 15
#define KBUF 768
#define BSLOT 32   // bucket slots per row/col (max observed degree ~22, Poisson(6))

typedef float vfloat4 __attribute__((ext_vector_type(4)));

__device__ __forceinline__ int mbcnt64(unsigned long long m) {
    int lo = __builtin_amdgcn_mbcnt_lo((unsigned int)m, 0u);
    return __builtin_amdgcn_mbcnt_hi((unsigned int)(m >> 32), lo);
}

// ---------------- init: zero cursors + xp = (x,y,z,|x|^2) + transpose Wp/Wq/Wk ----------------
__global__ __launch_bounds__(256) void k_init(int* __restrict__ cursR, int* __restrict__ cursC,
                                              const float* __restrict__ x, float4* __restrict__ xp,
                                              const float* __restrict__ Wp, const float* __restrict__ Wq,
                                              const float* __restrict__ Wk,
                                              float* __restrict__ WpT, float* __restrict__ WqT,
                                              float* __restrict__ WkT) {
    int tid = blockIdx.x * 256 + threadIdx.x;
    if (tid < N_NODES) {
        cursR[tid] = 0; cursC[tid] = 0;
        float a = x[tid * 3], b = x[tid * 3 + 1], c = x[tid * 3 + 2];
        xp[tid] = make_float4(a, b, c, a * a + b * b + c * c);
    }
    if (tid < H * H) {
        int k = tid >> 6, h = tid & 63;      // WT[k][h] = W[h][k]
        WpT[k * H + h] = Wp[h * H + k];
        WqT[k * H + h] = Wq[h * H + k];
        WkT[k * H + h] = Wk[h * H + k];
    }
}

// ---------------- kNN: 1 wave = 1 block; per-lane append buffers (no per-candidate ballots) ----------------
__global__ __launch_bounds__(64) void k_knn(const float4* __restrict__ xp, int* __restrict__ knn_idx,
                                            const int* __restrict__ edges, int* __restrict__ cursR,
                                            int* __restrict__ cursC, int* __restrict__ colRb,
                                            int* __restrict__ c2cb, float2* __restrict__ jav) {
    __shared__ unsigned long long cb[KBUF];        // 6144 B
    __shared__ unsigned long long plane[8][64];    // 4096 B  per-lane strips
    const int lane = threadIdx.x;
    const int i = blockIdx.x;

    // scatter piggyback: blocks 0..383 cover all 24576 edges (cursors zeroed by k_init)
    if (i < NE / 64) {
        int e = i * 64 + lane;
        int r = edges[e], c = edges[NE + e];
        int p = atomicAdd(&cursR[r], 1);
        int q = atomicAdd(&cursC[c], 1);
        if (p < BSLOT && q < BSLOT) {
            colRb[r * BSLOT + p] = c;
            c2cb[r * BSLOT + p] = c * BSLOT + q;
            ((int*)jav)[2 * (c * BSLOT + q)] = r;
        }
    }

    const float4 pi = xp[i];
    unsigned long long tauKey;
    int cnt;
    int mycnt = 0;

    auto sort64 = [&](unsigned long long key) -> unsigned long long {
#pragma unroll
        for (int k = 2; k <= 64; k <<= 1) {
#pragma unroll
            for (int j = 32; j > 0; j >>= 1) {
                if (j >= k) continue;
                unsigned long long other = __shfl_xor(key, j);
                bool asc = ((lane & k) == 0);
                bool takeMin = (((lane & j) == 0) == asc);
                bool less = key < other;
                key = (takeMin == less) ? key : other;
            }
        }
        return key;
    };

    auto tighten = [&]() {
        __builtin_amdgcn_wave_barrier();
        int n = (cnt + 63) >> 6;
        unsigned long long v[12];
        unsigned long long kmin = ~0ull;
#pragma unroll
        for (int t = 0; t < 12; ++t) {
            v[t] = ~0ull;
            if (t < n) {
                int s = t * 64 + lane;
                if (s < cnt) v[t] = cb[s];
                kmin = (v[t] < kmin) ? v[t] : kmin;
            }
        }
        unsigned long long T = __shfl(sort64(kmin), 14);
        __builtin_amdgcn_wave_barrier();
        int m = 0;
#pragma unroll
        for (int t = 0; t < 12; ++t) {
            if (t < n) {
                bool pred = (v[t] <= T);
                unsigned long long mk = __ballot(pred);
                if (pred) cb[m + mbcnt64(mk)] = v[t];
                m += __popcll(mk);
            }
        }
        cnt = m;
        tauKey = T;
        __builtin_amdgcn_wave_barrier();
    };

    auto merge = [&]() {
        __builtin_amdgcn_wave_barrier();
        int maxc = mycnt;
#pragma unroll
        for (int o = 32; o > 0; o >>= 1) { int u = __shfl_xor(maxc, o); maxc = (u > maxc) ? u : maxc; }
        for (int s = 0; s < maxc; ++s) {
            bool pred = (s < mycnt);
            unsigned long long mk = __ballot(pred);
            if (pred) cb[cnt + mbcnt64(mk)] = plane[s][lane];
            cnt += __popcll(mk);
        }
        mycnt = 0;
        __builtin_amdgcn_wave_barrier();
    };

    // iter 0: store all 256 keys; tau = 15th of sorted lane-mins (upper bound on exact 15th)
    {
        unsigned long long kmin = ~0ull;
#pragma unroll
        for (int t = 0; t < 4; ++t) {
            int j = t * 64 + lane;
            float4 pj = xp[j];
            float d = pi.w + pj.w - 2.0f * (pi.x * pj.x + pi.y * pj.y + pi.z * pj.z);
            unsigned long long key = ((unsigned long long)__float_as_uint(d) << 32) | (unsigned)j;
            if (j == i) key = ~0ull;
            cb[j] = key;
            kmin = (key < kmin) ? key : kmin;
        }
        cnt = 256;
        tauKey = __shfl(sort64(kmin), 14);
        __builtin_amdgcn_wave_barrier();
    }

    // iters 1..15: per-lane conditional appends only — no cross-lane ops in the hot path
    for (int iter = 1; iter < 16; ++iter) {
        const int jb = iter * 256;
        float4 p0 = xp[jb + lane];
        float4 p1 = xp[jb + 64 + lane];
        float4 p2 = xp[jb + 128 + lane];
        float4 p3 = xp[jb + 192 + lane];
        float d0 = pi.w + p0.w - 2.0f * (pi.x * p0.x + pi.y * p0.y + pi.z * p0.z);
        float d1 = pi.w + p1.w - 2.0f * (pi.x * p1.x + pi.y * p1.y + pi.z * p1.z);
        float d2 = pi.w + p2.w - 2.0f * (pi.x * p2.x + pi.y * p2.y + pi.z * p2.z);
        float d3 = pi.w + p3.w - 2.0f * (pi.x * p3.x + pi.y * p3.y + pi.z * p3.z);
#pragma unroll
        for (int t = 0; t < 4; ++t) {
            float d = (t == 0) ? d0 : (t == 1) ? d1 : (t == 2) ? d2 : d3;
            int j = jb + t * 64 + lane;
            unsigned long long key = ((unsigned long long)__float_as_uint(d) << 32) | (unsigned)j;
            if ((key < tauKey) && (j != i)) { plane[mycnt][lane] = key; ++mycnt; }
        }
        if (__any(mycnt > 4)) { merge(); tighten(); }   // keeps start-of-iter mycnt<=4 -> <=8 slots
    }

    merge();
    tighten();
    if (cnt > 64) tighten();
    unsigned long long fin = (lane < cnt) ? cb[lane] : ~0ull;
    fin = sort64(fin);
    if (lane < KNN) knn_idx[i * KNN + lane] = (int)(fin & 0xffffffffu);
}

// ---------------- DevConv max-agg + WpT/WqT/WkT (coalesced): 4 waves/block, wave per node ----------------
__global__ __launch_bounds__(256) void k_agg_feat_qk(const float4* __restrict__ xp,
                                                     const int* __restrict__ cursR, const int* __restrict__ colRb,
                                                     const int* __restrict__ knn_idx, const float* __restrict__ Wt,
                                                     const float* __restrict__ WpT, const float* __restrict__ WqT,
                                                     const float* __restrict__ WkT,
                                                     float* __restrict__ qb, float* __restrict__ kb) {
    __shared__ float mrow[4][64];
    __shared__ float frow[4][64];
    int w = threadIdx.x >> 6, lane = threadIdx.x & 63;
    int i = blockIdx.x * 4 + w;
    float w0 = Wt[lane * 3], w1 = Wt[lane * 3 + 1], w2 = Wt[lane * 3 + 2];
    float4 pi = xp[i];
    float m = -INFINITY;
    int deg = cursR[i];
    for (int s = 0; s < deg; ++s) {
        float4 pj = xp[colRb[i * BSLOT + s]];
        m = fmaxf(m, w0 * (pj.x - pi.x) + w1 * (pj.y - pi.y) + w2 * (pj.z - pi.z));
    }
    for (int t = 0; t < KNN; ++t) {
        float4 pj = xp[knn_idx[i * KNN + t]];
        m = fmaxf(m, w0 * (pj.x - pi.x) + w1 * (pj.y - pi.y) + w2 * (pj.z - pi.z));
    }
    if (!(m > -INFINITY)) m = 0.0f;
    mrow[w][lane] = m;
    __syncthreads();
    float f = 0.f;
    for (int k2 = 0; k2 < H; ++k2) f += WpT[k2 * H + lane] * mrow[w][k2];   // coalesced
    frow[w][lane] = f;
    __syncthreads();
    float qv = 0.f, kv = 0.f;
    for (int k2 = 0; k2 < H; ++k2) {
        float fr = frow[w][k2];
        qv += WqT[k2 * H + lane] * fr;                                      // coalesced
        kv += WkT[k2 * H + lane] * fr;                                      // coalesced
    }
    qb[i * H + lane] = qv;
    kb[i * H + lane] = kv;
}

// ---------------- fused attention + softmax: 4 waves per block, fully in-register ----------------
__global__ __launch_bounds__(256) void k_attsm(const int* __restrict__ cursR, const int* __restrict__ colRb,
                                               const int* __restrict__ c2cb,
                                               const float* __restrict__ qb, const float* __restrict__ kb,
                                               float* __restrict__ attnRb, float2* __restrict__ jav) {
    int w = threadIdx.x >> 6, lane = threadIdx.x & 63;
    int i = blockIdx.x * 4 + w;
    int deg = cursR[i];
    if (deg == 0) return;                     // wave-level exit; kernel has no barriers
    float qv = qb[i * H + lane];
    float m = -INFINITY, myv = 0.f;
    for (int s = 0; s < deg; ++s) {
        int c = colRb[i * BSLOT + s];         // wave-uniform broadcast
        float v = qv * kb[c * H + lane];      // coalesced
#pragma unroll
        for (int o = 32; o > 0; o >>= 1) v += __shfl_xor(v, o);
        if (lane == s) myv = v;               // lane s keeps score s
        m = fmaxf(m, v);                      // wave-uniform
    }
    float ex = (lane < deg) ? expf(myv - m) : 0.f;
    float den = ex;
#pragma unroll
    for (int o = 32; o > 0; o >>= 1) den += __shfl_xor(den, o);
    if (lane < deg) {
        float a = ex / den;
        attnRb[i * BSLOT + lane] = a;
        ((float*)jav)[2 * c2cb[i * BSLOT + lane] + 1] = a;   // av into jav.y
    }
}

// ---------------- final: block per row; parallel prep + (s,a)-parallel leaves; no pair list ----------------
__global__ __launch_bounds__(256) void k_final_row(const int* __restrict__ cursR, const int* __restrict__ cursC,
                                                   const int* __restrict__ colRb, const float* __restrict__ attnRb,
                                                   const float2* __restrict__ jav,
                                                   float* __restrict__ out) {
    __shared__ __align__(16) float Orow[N_NODES];
    __shared__ int   cS[BSLOT];
    __shared__ float svS[BSLOT];
    __shared__ int   dS[BSLOT];
    int r = blockIdx.x;
    int tid = threadIdx.x;
    vfloat4* O4 = (vfloat4*)Orow;
    vfloat4 z = {0.f, 0.f, 0.f, 0.f};
    int deg = cursR[r];

    if (tid >= 64) {
        // waves 1-3: zero the accumulator row
        for (int t = tid - 64; t < N_NODES / 4; t += 192) O4[t] = z;
    } else if (tid < deg) {
        // wave 0, lanes 0..deg-1 in parallel: neighbor c, its attn, its A-row degree
        int c = colRb[r * BSLOT + tid];
        cS[tid]  = c;
        svS[tid] = attnRb[r * BSLOT + tid];
        dS[tid]  = cursR[c];
    }
    __syncthreads();

    // leaf phase: thread per (s, a) slot; a strides the A-row of neighbor s
    int tot = deg * BSLOT;
    for (int idx = tid; idx < tot; idx += 256) {
        int s = idx >> 5, a = idx & (BSLOT - 1);
        if (a < dS[s]) {
            int c2 = colRb[cS[s] * BSLOT + a];
            float sv = svS[s];
            int b1 = cursC[c2];
            for (int b = 0; b < b1; ++b) {
                float2 v = jav[c2 * BSLOT + b];
                atomicAdd(&Orow[__float_as_int(v.x)], sv * v.y);
            }
        }
    }
    __syncthreads();

    vfloat4* o4 = (vfloat4*)(out + (size_t)r * N_NODES);
#pragma unroll
    for (int t = 0; t < N_NODES / 4 / 256; ++t)
        __builtin_nontemporal_store(O4[tid + t * 256], &o4[tid + t * 256]);
}

extern "C" void kernel_launch(void* const* d_in, const int* in_sizes, int n_in,
                              void* d_out, int out_size, void* d_ws, size_t ws_size,
                              hipStream_t stream) {
    const float* x    = (const float*)d_in[0];
    const int* edges  = (const int*)d_in[1];
    const float* Wt   = (const float*)d_in[2];
    const float* Wp   = (const float*)d_in[3];
    const float* Wq   = (const float*)d_in[4];
    const float* Wk   = (const float*)d_in[5];
    float* out = (float*)d_out;

    char* w = (char*)d_ws;
    size_t off = 0;
    auto alloc = [&](size_t bytes) -> void* {
        void* p = w + off;
        off += (bytes + 255) & ~(size_t)255;
        return p;
    };
    float4* xp      = (float4*)alloc((size_t)N_NODES * 16);
    int*   knn      = (int*)  alloc((size_t)N_NODES * KNN * 4);
    float* qb       = (float*)alloc((size_t)N_NODES * H * 4);
    float* kb       = (float*)alloc((size_t)N_NODES * H * 4);
    int*   cursR    = (int*)  alloc((size_t)N_NODES * 4);
    int*   cursC    = (int*)  alloc((size_t)N_NODES * 4);
    int*   colRb    = (int*)  alloc((size_t)N_NODES * BSLOT * 4);
    int*   c2cb     = (int*)  alloc((size_t)N_NODES * BSLOT * 4);
    float* attnRb   = (float*)alloc((size_t)N_NODES * BSLOT * 4);
    float2* jav     = (float2*)alloc((size_t)N_NODES * BSLOT * 8);
    float* WpT      = (float*)alloc((size_t)H * H * 4);
    float* WqT      = (float*)alloc((size_t)H * H * 4);
    float* WkT      = (float*)alloc((size_t)H * H * 4);

    k_init<<<(N_NODES + 255) / 256, 256, 0, stream>>>(cursR, cursC, x, xp, Wp, Wq, Wk, WpT, WqT, WkT);
    k_knn<<<N_NODES, 64, 0, stream>>>(xp, knn, edges, cursR, cursC, colRb, c2cb, jav);
    k_agg_feat_qk<<<N_NODES / 4, 256, 0, stream>>>(xp, cursR, colRb, knn, Wt, WpT, WqT, WkT, qb, kb);
    k_attsm<<<N_NODES / 4, 256, 0, stream>>>(cursR, colRb, c2cb, qb, kb, attnRb, jav);
    k_final_row<<<N_NODES, 256, 0, stream>>>(cursR, cursC, colRb, attnRb, jav, out);
}